// Round 2
// baseline (252.981 us; speedup 1.0000x reference)
//
#include <hip/hip_runtime.h>
#include <math.h>

#define NUM_GT   128
#define NUM_PROP 512
#define IMG_H    520
#define IMG_W    704
#define MS       28
#define LOGITS_N (NUM_PROP * 2 * MS * MS)   // 802816

// ws layout (16 bytes, zeroed each launch):
//   acc[0] = masked bce sum
//   acc[1] = npos
//   acc[2] = sum(mask_logits^2)
//   acc[3] = done-counter (as unsigned)

__global__ __launch_bounds__(256)
void fused_kernel(const float* __restrict__ proposals,
                  const float* __restrict__ gt_boxes,
                  const float* __restrict__ gt_masks,
                  const float* __restrict__ mask_logits,
                  float* __restrict__ acc,
                  float* __restrict__ out) {
    const int p = blockIdx.x;
    const int t = threadIdx.x;

    __shared__ float s_gb[NUM_GT * 4];
    __shared__ float s_iou[NUM_GT];
    __shared__ int   s_idx[NUM_GT];
    __shared__ int   s_g;
    __shared__ float s_pos;
    __shared__ int   s_x0[MS], s_x1[MS], s_y0[MS], s_y1[MS];
    __shared__ float s_wx[MS], s_wy[MS];
    __shared__ float red_bce[4], red_sq[4];

    // ---- stage gt_boxes to LDS ----
    for (int i = t; i < NUM_GT * 4; i += 256) s_gb[i] = gt_boxes[i];

    // ---- sq part: this block's contiguous logits slice (2*784 floats) ----
    const float4* lp = (const float4*)(mask_logits + (size_t)p * 2 * MS * MS);
    float sqacc = 0.0f;
    for (int i = t; i < (2 * MS * MS) / 4; i += 256) {   // 392 float4
        float4 x = lp[i];
        sqacc += x.x * x.x + x.y * x.y + x.z * x.z + x.w * x.w;
    }

    __syncthreads();

    // ---- match: thread g computes IoU(p, g) for g < 128 ----
    const float ax1 = proposals[p * 4 + 0];
    const float ay1 = proposals[p * 4 + 1];
    const float ax2 = proposals[p * 4 + 2];
    const float ay2 = proposals[p * 4 + 3];
    if (t < NUM_GT) {
        float area_a = (ax2 - ax1) * (ay2 - ay1);
        float bx1 = s_gb[t * 4 + 0];
        float by1 = s_gb[t * 4 + 1];
        float bx2 = s_gb[t * 4 + 2];
        float by2 = s_gb[t * 4 + 3];
        float area_b = (bx2 - bx1) * (by2 - by1);
        float w = fmaxf(fminf(ax2, bx2) - fmaxf(ax1, bx1), 0.0f);
        float h = fmaxf(fminf(ay2, by2) - fmaxf(ay1, by1), 0.0f);
        float inter = w * h;
        s_iou[t] = inter / (area_a + area_b - inter);
        s_idx[t] = t;
    }
    __syncthreads();

    // argmax tree-reduce, first-index tie-break (jnp.argmax)
    for (int s = NUM_GT / 2; s > 0; s >>= 1) {
        if (t < s) {
            float a = s_iou[t], b = s_iou[t + s];
            int ia = s_idx[t], ib = s_idx[t + s];
            if (b > a || (b == a && ib < ia)) { s_iou[t] = b; s_idx[t] = ib; }
        }
        __syncthreads();
    }
    if (t == 0) {
        s_g = s_idx[0];
        s_pos = (s_iou[0] > 0.5f) ? 1.0f : 0.0f;
    }
    __syncthreads();

    const int g = s_g;

    // ---- crop-resize coordinate tables (from matched gt box) ----
    if (t < MS) {
        float b0 = s_gb[g * 4 + 0];
        float b1 = s_gb[g * 4 + 1];
        float b2 = s_gb[g * 4 + 2];
        float b3 = s_gb[g * 4 + 3];
        int x1 = min(max((int)b0, 0), IMG_W - 1);    // (int) = trunc toward 0 = astype(int32)
        int y1 = min(max((int)b1, 0), IMG_H - 1);
        int x2 = max(x1 + 1, min((int)b2, IMG_W));
        int y2 = max(y1 + 1, min((int)b3, IMG_H));
        int cwi = x2 - x1;
        int chi = y2 - y1;
        float cw = (float)cwi;
        float ch = (float)chi;

        float j = (float)t + 0.5f;
        float sx = fminf(fmaxf(j * cw / 28.0f - 0.5f, 0.0f), cw - 1.0f);
        float x0f = floorf(sx);
        int x0i = (int)x0f;
        s_wx[t] = sx - x0f;
        s_x0[t] = x0i + x1;
        s_x1[t] = min(x0i + 1, cwi - 1) + x1;

        float sy = fminf(fmaxf(j * ch / 28.0f - 0.5f, 0.0f), ch - 1.0f);
        float y0f = floorf(sy);
        int y0i = (int)y0f;
        s_wy[t] = sy - y0f;
        s_y0[t] = y0i + y1;
        s_y1[t] = min(y0i + 1, chi - 1) + y1;
    }
    __syncthreads();

    // ---- bilinear sample + BCE over 28x28 ----
    const float* m  = gt_masks + (size_t)g * IMG_H * IMG_W;
    const float* lg = mask_logits + ((size_t)p * 2 + 1) * (MS * MS);

    float bceacc = 0.0f;
    for (int idx = t; idx < MS * MS; idx += 256) {
        int i = idx / MS;
        int j = idx - i * MS;
        float wx = s_wx[j], wy = s_wy[i];
        const float* r0 = m + (size_t)s_y0[i] * IMG_W;
        const float* r1 = m + (size_t)s_y1[i] * IMG_W;
        int cx0 = s_x0[j], cx1 = s_x1[j];
        float v00 = r0[cx0], v01 = r0[cx1];
        float v10 = r1[cx0], v11 = r1[cx1];
        float top = (1.0f - wx) * v00 + wx * v01;
        float bot = (1.0f - wx) * v10 + wx * v11;
        float tv  = (1.0f - wy) * top + wy * bot;
        float l = lg[idx];
        bceacc += fmaxf(l, 0.0f) - l * tv + log1pf(expf(-fabsf(l)));
    }

    // ---- block reduce bce + sq together ----
    float vb = bceacc, vs = sqacc;
    #pragma unroll
    for (int o = 32; o > 0; o >>= 1) {
        vb += __shfl_down(vb, o, 64);
        vs += __shfl_down(vs, o, 64);
    }
    int lane = t & 63, wid = t >> 6;
    if (lane == 0) { red_bce[wid] = vb; red_sq[wid] = vs; }
    __syncthreads();

    if (t == 0) {
        float bce_s = red_bce[0] + red_bce[1] + red_bce[2] + red_bce[3];
        float sq_s  = red_sq[0] + red_sq[1] + red_sq[2] + red_sq[3];
        atomicAdd(acc + 0, bce_s * s_pos);
        atomicAdd(acc + 1, s_pos);
        atomicAdd(acc + 2, sq_s);
        __threadfence();
        unsigned done = atomicAdd((unsigned*)(acc + 3), 1u);
        if (done == NUM_PROP - 1) {
            // device-scope atomic reads (all prior adds ordered by fences+counter)
            float bce  = atomicAdd(acc + 0, 0.0f);
            float npos = atomicAdd(acc + 1, 0.0f);
            float sq   = atomicAdd(acc + 2, 0.0f);
            float loss_pos = bce / (fmaxf(npos, 1.0f) * (float)(MS * MS));
            float loss_neg = (sq / (float)LOGITS_N) * 0.01f;
            out[0] = (npos > 0.0f) ? loss_pos : loss_neg;
        }
    }
}

extern "C" void kernel_launch(void* const* d_in, const int* in_sizes, int n_in,
                              void* d_out, int out_size, void* d_ws, size_t ws_size,
                              hipStream_t stream) {
    const float* proposals   = (const float*)d_in[0];
    const float* gt_boxes    = (const float*)d_in[1];
    const float* gt_masks    = (const float*)d_in[2];
    const float* mask_logits = (const float*)d_in[3];
    float* out = (float*)d_out;
    float* acc = (float*)d_ws;

    hipMemsetAsync(d_ws, 0, 16, stream);
    fused_kernel<<<NUM_PROP, 256, 0, stream>>>(proposals, gt_boxes, gt_masks,
                                               mask_logits, acc, out);
}